// Round 1
// baseline (796.060 us; speedup 1.0000x reference)
//
#include <hip/hip_runtime.h>
#include <math.h>

// Problem: B=65536 rows, DIM=256, OUT=10.
// Pipeline: z = x@w_in + b_in; 4x { z = (z + tanh(z) + b_i) @ inv(W_i) };
//           out = softmax(z@w_out + b_out).
// Newton on a linear system converges in one step => z = c @ W^{-1} exactly.

// ---------------- Phase 1: Newton-Schulz inverse of W1..W4 ----------------

__global__ void inv_init_k(const float* __restrict__ w1, const float* __restrict__ w2,
                           const float* __restrict__ w3, const float* __restrict__ w4,
                           float* __restrict__ X) {
  int idx = blockIdx.x * 256 + threadIdx.x;  // 0 .. 4*65536-1
  int m = idx >> 16;
  int rc = idx & 65535;
  const float* W = (m == 0) ? w1 : (m == 1) ? w2 : (m == 2) ? w3 : w4;
  int r = rc >> 8, c = rc & 255;
  X[idx] = ((r == c) ? 2.0f : 0.0f) - W[rc];
}

// T = W @ X (batched over 4 matrices), 256x256x256
__global__ void ns_wx_k(const float* __restrict__ w1, const float* __restrict__ w2,
                        const float* __restrict__ w3, const float* __restrict__ w4,
                        const float* __restrict__ X, float* __restrict__ T) {
  __shared__ float As[16][17];
  __shared__ float Bs[16][17];
  int m = blockIdx.z;
  const float* W = (m == 0) ? w1 : (m == 1) ? w2 : (m == 2) ? w3 : w4;
  const float* Xm = X + m * 65536;
  float* Tm = T + m * 65536;
  int tx = threadIdx.x, ty = threadIdx.y;
  int row = blockIdx.y * 16 + ty, col = blockIdx.x * 16 + tx;
  float acc = 0.f;
  for (int k0 = 0; k0 < 256; k0 += 16) {
    As[ty][tx] = W[row * 256 + k0 + tx];
    Bs[ty][tx] = Xm[(k0 + ty) * 256 + col];
    __syncthreads();
#pragma unroll
    for (int k = 0; k < 16; ++k) acc = fmaf(As[ty][k], Bs[k][tx], acc);
    __syncthreads();
  }
  Tm[row * 256 + col] = acc;
}

// Xn = 2*Xc - Xc @ T (batched over 4)
__global__ void ns_update_k(const float* __restrict__ Xc, const float* __restrict__ T,
                            float* __restrict__ Xn) {
  __shared__ float As[16][17];
  __shared__ float Bs[16][17];
  int m = blockIdx.z;
  const float* Am = Xc + m * 65536;
  const float* Bm = T + m * 65536;
  float* Om = Xn + m * 65536;
  int tx = threadIdx.x, ty = threadIdx.y;
  int row = blockIdx.y * 16 + ty, col = blockIdx.x * 16 + tx;
  float acc = 0.f;
  for (int k0 = 0; k0 < 256; k0 += 16) {
    As[ty][tx] = Am[row * 256 + k0 + tx];
    Bs[ty][tx] = Bm[(k0 + ty) * 256 + col];
    __syncthreads();
#pragma unroll
    for (int k = 0; k < 16; ++k) acc = fmaf(As[ty][k], Bs[k][tx], acc);
    __syncthreads();
  }
  Om[row * 256 + col] = 2.f * Am[row * 256 + col] - acc;
}

// ---------------- Phase 2: fused pipeline ----------------
// 64 rows per workgroup, z tile resident in LDS (64x256 fp32 = 64KB -> 2 WG/CU).
// Thread micro-tile: 8 rows x 8 cols (cols = 4*tcol..+3 and 4*tcol+128..+131).

__global__ __launch_bounds__(256) void fused_k(
    const float* __restrict__ x,
    const float* __restrict__ w_in, const float* __restrict__ b_in,
    const float* __restrict__ Winv,  // 4 x 256 x 256 (inverses)
    const float* __restrict__ b1, const float* __restrict__ b2,
    const float* __restrict__ b3, const float* __restrict__ b4,
    const float* __restrict__ w_out, const float* __restrict__ b_out,
    float* __restrict__ out) {
  __shared__ float zA[64][256];
  const int t = threadIdx.x;
  const int tcol = t & 31;   // 0..31
  const int trow = t >> 5;   // 0..7
  const int row0 = trow * 8;
  const int c0 = tcol * 4;   // cols c0..c0+3 and c0+128..c0+131
  const int grow0 = blockIdx.x * 64;

  // ---- load x tile into LDS (fully coalesced float4) ----
  for (int it = 0; it < 16; ++it) {
    int e = it * 1024 + t * 4;
    int r = e >> 8, c = e & 255;
    float4 v = *(const float4*)(x + (grow0 + r) * 256 + c);
    *(float4*)&zA[r][c] = v;
  }

  const float* Ws[5] = {w_in, Winv, Winv + 65536, Winv + 131072, Winv + 196608};
  const float* bs[4] = {b1, b2, b3, b4};

  __attribute__((aligned(16))) float acc[8][8];

  for (int layer = 0; layer < 5; ++layer) {
    __syncthreads();  // tile (x or previous writeback) visible to all
    if (layer > 0) {
      // c = z + tanh(z) + b  (in place; each thread owns its elements)
      const float* bp = bs[layer - 1];
      int r = t >> 2;
      int cb = (t & 3) * 64;
#pragma unroll 4
      for (int i = 0; i < 16; ++i) {
        float4 v = *(float4*)&zA[r][cb + i * 4];
        float4 bb = *(const float4*)(bp + cb + i * 4);
        v.x += tanhf(v.x) + bb.x;
        v.y += tanhf(v.y) + bb.y;
        v.z += tanhf(v.z) + bb.z;
        v.w += tanhf(v.w) + bb.w;
        *(float4*)&zA[r][cb + i * 4] = v;
      }
      __syncthreads();
    }

    const float* __restrict__ Wp = Ws[layer];
#pragma unroll
    for (int r = 0; r < 8; ++r)
#pragma unroll
      for (int j = 0; j < 8; ++j) acc[r][j] = 0.f;

    for (int k0 = 0; k0 < 256; k0 += 4) {
      __attribute__((aligned(16))) float cf[8][4];
#pragma unroll
      for (int r = 0; r < 8; ++r)
        *(float4*)&cf[r][0] = *(const float4*)&zA[row0 + r][k0];
#pragma unroll
      for (int kk = 0; kk < 4; ++kk) {
        const float* wrow = Wp + (k0 + kk) * 256;
        float4 w0 = *(const float4*)(wrow + c0);
        float4 w1 = *(const float4*)(wrow + c0 + 128);
#pragma unroll
        for (int r = 0; r < 8; ++r) {
          float cv = cf[r][kk];
          acc[r][0] = fmaf(cv, w0.x, acc[r][0]);
          acc[r][1] = fmaf(cv, w0.y, acc[r][1]);
          acc[r][2] = fmaf(cv, w0.z, acc[r][2]);
          acc[r][3] = fmaf(cv, w0.w, acc[r][3]);
          acc[r][4] = fmaf(cv, w1.x, acc[r][4]);
          acc[r][5] = fmaf(cv, w1.y, acc[r][5]);
          acc[r][6] = fmaf(cv, w1.z, acc[r][6]);
          acc[r][7] = fmaf(cv, w1.w, acc[r][7]);
        }
      }
    }
    __syncthreads();  // all reads of zA done before overwrite
    if (layer == 0) {
      float4 bb0 = *(const float4*)(b_in + c0);
      float4 bb1 = *(const float4*)(b_in + c0 + 128);
#pragma unroll
      for (int r = 0; r < 8; ++r) {
        acc[r][0] += bb0.x; acc[r][1] += bb0.y; acc[r][2] += bb0.z; acc[r][3] += bb0.w;
        acc[r][4] += bb1.x; acc[r][5] += bb1.y; acc[r][6] += bb1.z; acc[r][7] += bb1.w;
      }
    }
#pragma unroll
    for (int r = 0; r < 8; ++r) {
      *(float4*)&zA[row0 + r][c0] = *(float4*)&acc[r][0];
      *(float4*)&zA[row0 + r][c0 + 128] = *(float4*)&acc[r][4];
    }
  }

  __syncthreads();

  // ---- output layer (64x10) + softmax ----
  float lg[3];
  int eid[3];
  int ne = 0;
  for (int e = t; e < 640; e += 256) {
    int r = e / 10;
    int c = e - r * 10;
    float a = b_out[c];
    for (int k = 0; k < 256; ++k) a = fmaf(zA[r][k], w_out[k * 10 + c], a);
    lg[ne] = a;
    eid[ne] = e;
    ++ne;
  }
  __syncthreads();  // all zA reads done; reuse zA as logit buffer [64][12]
  float* lbuf = &zA[0][0];
  for (int i = 0; i < ne; ++i) {
    int r = eid[i] / 10;
    int c = eid[i] - r * 10;
    lbuf[r * 12 + c] = lg[i];
  }
  __syncthreads();
  if (t < 64) {
    float l[10];
    float m = -1e30f;
#pragma unroll
    for (int c = 0; c < 10; ++c) {
      l[c] = lbuf[t * 12 + c];
      m = fmaxf(m, l[c]);
    }
    float s = 0.f;
#pragma unroll
    for (int c = 0; c < 10; ++c) {
      l[c] = expf(l[c] - m);
      s += l[c];
    }
    float inv = 1.0f / s;
    float* op = out + (grow0 + t) * 10;
#pragma unroll
    for (int c = 0; c < 10; ++c) op[c] = l[c] * inv;
  }
}

extern "C" void kernel_launch(void* const* d_in, const int* in_sizes, int n_in,
                              void* d_out, int out_size, void* d_ws, size_t ws_size,
                              hipStream_t stream) {
  const float* x     = (const float*)d_in[0];
  const float* w_in  = (const float*)d_in[1];
  const float* b_in  = (const float*)d_in[2];
  const float* w_out = (const float*)d_in[3];
  const float* b_out = (const float*)d_in[4];
  const float* w1 = (const float*)d_in[5];
  const float* b1 = (const float*)d_in[6];
  const float* w2 = (const float*)d_in[7];
  const float* b2 = (const float*)d_in[8];
  const float* w3 = (const float*)d_in[9];
  const float* b3 = (const float*)d_in[10];
  const float* w4 = (const float*)d_in[11];
  const float* b4 = (const float*)d_in[12];
  float* out = (float*)d_out;

  // workspace: A (1MB), B (1MB), T (1MB) of fp32 256x256x4
  float* A  = (float*)d_ws;
  float* Bw = A + 262144;
  float* T  = A + 524288;

  inv_init_k<<<1024, 256, 0, stream>>>(w1, w2, w3, w4, A);  // X0 = 2I - W
  float* cur = A;
  float* nxt = Bw;
  for (int it = 0; it < 4; ++it) {  // Newton-Schulz: X <- X(2I - WX)
    ns_wx_k<<<dim3(16, 16, 4), dim3(16, 16), 0, stream>>>(w1, w2, w3, w4, cur, T);
    ns_update_k<<<dim3(16, 16, 4), dim3(16, 16), 0, stream>>>(cur, T, nxt);
    float* tmp = cur; cur = nxt; nxt = tmp;
  }

  fused_k<<<1024, 256, 0, stream>>>(x, w_in, b_in, cur, b1, b2, b3, b4,
                                    w_out, b_out, out);
}

// Round 2
// 309.152 us; speedup vs baseline: 2.5750x; 2.5750x over previous
//
#include <hip/hip_runtime.h>
#include <math.h>

// B=65536 rows, DIM=256, OUT=10.
// z = x@w_in + b_in; 4x { z = (z + tanh(z) + b_i) @ inv(W_i) }; out = softmax(z@w_out + b_out).
// Newton on a linear system converges in one step => z = c @ W^{-1} exactly.
// This round: split-bf16 (Markidis) MFMA for all big GEMMs; weights pre-packed
// into MFMA B-fragment order; z resident in LDS as swizzled hi/lo bf16 planes.

typedef __attribute__((ext_vector_type(8))) short short8;
typedef __attribute__((ext_vector_type(4))) float f32x4;

// ---- helpers ----
__device__ __forceinline__ unsigned short bf16_rn(float f) {
  unsigned u = __float_as_uint(f);
  return (unsigned short)((u + 0x7fffu + ((u >> 16) & 1u)) >> 16);
}
__device__ __forceinline__ void split1(float c, unsigned short& h, unsigned short& l) {
  unsigned short hb = bf16_rn(c);
  float hf = __uint_as_float(((unsigned)hb) << 16);
  l = bf16_rn(c - hf);
  h = hb;
}
__device__ __forceinline__ float tanhf_fast(float x) {
  float ax = fabsf(x);
  float e = __expf(2.0f * ax);          // inf-safe: large ax -> e=inf -> r=1
  float r = 1.0f - 2.0f * (1.0f / (e + 1.0f));
  return copysignf(r, x);
}

// ---------------- Phase 1a: Newton-Schulz inverse (2 iterations) ----------------
// One generic 256x256 GEMM (batched over 4 matrices) with optional (2I - M)
// transforms on A and/or B. 32x32 tile, 2x2 micro, grid (8,8,4).
__global__ __launch_bounds__(256) void ns_gemm_k(
    const float* __restrict__ a0, const float* __restrict__ a1,
    const float* __restrict__ a2, const float* __restrict__ a3,
    const float* __restrict__ b0, const float* __restrict__ b1,
    const float* __restrict__ b2, const float* __restrict__ b3,
    float* __restrict__ D, int aMode, int bMode) {
  __shared__ float As[32][17];
  __shared__ float Bs[16][33];
  int m = blockIdx.z;
  const float* A = (m == 0) ? a0 : (m == 1) ? a1 : (m == 2) ? a2 : a3;
  const float* B = (m == 0) ? b0 : (m == 1) ? b1 : (m == 2) ? b2 : b3;
  float* Dm = D + m * 65536;
  int t = threadIdx.x;
  int tx = t & 15, ty = t >> 4;
  int row0 = blockIdx.y * 32, col0 = blockIdx.x * 32;
  float acc00 = 0.f, acc01 = 0.f, acc10 = 0.f, acc11 = 0.f;
  for (int k0 = 0; k0 < 256; k0 += 16) {
#pragma unroll
    for (int half = 0; half < 2; ++half) {
      int e = t + half * 256;
      int r = e >> 4, kk = e & 15;
      float v = A[(row0 + r) * 256 + k0 + kk];
      if (aMode) v = (((row0 + r) == (k0 + kk)) ? 2.0f : 0.0f) - v;
      As[r][kk] = v;
      int k2 = e >> 5, c = e & 31;
      float w = B[(k0 + k2) * 256 + col0 + c];
      if (bMode) w = (((k0 + k2) == (col0 + c)) ? 2.0f : 0.0f) - w;
      Bs[k2][c] = w;
    }
    __syncthreads();
#pragma unroll
    for (int kk = 0; kk < 16; ++kk) {
      float av0 = As[ty][kk], av1 = As[ty + 16][kk];
      float bv0 = Bs[kk][tx], bv1 = Bs[kk][tx + 16];
      acc00 = fmaf(av0, bv0, acc00);
      acc01 = fmaf(av0, bv1, acc01);
      acc10 = fmaf(av1, bv0, acc10);
      acc11 = fmaf(av1, bv1, acc11);
    }
    __syncthreads();
  }
  Dm[(row0 + ty) * 256 + col0 + tx] = acc00;
  Dm[(row0 + ty) * 256 + col0 + tx + 16] = acc01;
  Dm[(row0 + ty + 16) * 256 + col0 + tx] = acc10;
  Dm[(row0 + ty + 16) * 256 + col0 + tx + 16] = acc11;
}

// ---------------- Phase 1b: pack weights into MFMA B-fragment order ----------------
// Layout (dwords): layer*65536 + kc*8192 + nt*512 + plane*256 + lane*4 + d
// layer 0..4 = w_in, Winv1..4 (256 cols, 16 n-tiles); then w_out at 5*65536:
// kc*512 + plane*256 + lane*4 + d (single n-tile, cols >=10 zero).
// Fragment: lane (quad=lane>>4, n=lane&15) holds B[kc*32+quad*8+j][ntile*16+n], j=0..7;
// dword d packs elements j=2d (lo16) and j=2d+1 (hi16). plane0=hi half, plane1=lo half.
__device__ __forceinline__ unsigned pack2(float v0, float v1, int plane) {
  unsigned short h0, l0, h1, l1;
  split1(v0, h0, l0);
  split1(v1, h1, l1);
  unsigned a = plane ? l0 : h0;
  unsigned b = plane ? l1 : h1;
  return (b << 16) | a;
}
__global__ void pack_k(const float* __restrict__ w_in, const float* __restrict__ Xinv,
                       const float* __restrict__ w_out, unsigned* __restrict__ pk) {
  int idx = blockIdx.x * 256 + threadIdx.x;
  if (idx < 5 * 65536) {
    int layer = idx >> 16;
    int rem = idx & 65535;
    int kc = rem >> 13;
    int nt = (rem >> 9) & 15;
    int plane = (rem >> 8) & 1;
    int lane = (rem >> 2) & 63;
    int d = rem & 3;
    int n = nt * 16 + (lane & 15);
    int kb = kc * 32 + (lane >> 4) * 8 + d * 2;
    const float* W = (layer == 0) ? w_in : (Xinv + (layer - 1) * 65536);
    pk[idx] = pack2(W[kb * 256 + n], W[(kb + 1) * 256 + n], plane);
  } else {
    int r2 = idx - 5 * 65536;  // w_out: 4096 dwords
    int kc = r2 >> 9;
    int plane = (r2 >> 8) & 1;
    int lane = (r2 >> 2) & 63;
    int d = r2 & 3;
    int n = lane & 15;
    int kb = kc * 32 + (lane >> 4) * 8 + d * 2;
    float v0 = (n < 10) ? w_out[kb * 10 + n] : 0.0f;
    float v1 = (n < 10) ? w_out[(kb + 1) * 10 + n] : 0.0f;
    pk[idx] = pack2(v0, v1, plane);
  }
}

// ---------------- Phase 2: fused pipeline (MFMA) ----------------
// 64 rows/block, 256 threads = 4 waves; wave w owns cols [w*64, w*64+64).
// z lives in LDS as two bf16 planes (hi/lo), 16B-chunk XOR swizzle:
//   idx16(m,k) = m*256 + ((k>>3) ^ (m&31))*8 + (k&7)
// A-frag for (m, kc, quad) = 16 contiguous bytes at chunk (kc*4+quad)^(m&31).
__global__ __launch_bounds__(256, 2) void fused_k(
    const float* __restrict__ x, const unsigned* __restrict__ pk,
    const float* __restrict__ b_in,
    const float* __restrict__ b1, const float* __restrict__ b2,
    const float* __restrict__ b3, const float* __restrict__ b4,
    const float* __restrict__ b_out, float* __restrict__ out) {
  __shared__ unsigned short zh[64 * 256];
  __shared__ unsigned short zl[64 * 256];
  const int t = threadIdx.x;
  const int ln = t & 63;
  const int wv = t >> 6;
  const int quad = ln >> 4;
  const int n16 = ln & 15;
  const int grow0 = blockIdx.x * 64;

  // ---- stage x as split bf16 planes (coalesced float4 reads) ----
#pragma unroll
  for (int i = 0; i < 16; ++i) {
    int e = i * 1024 + t * 4;
    int r = e >> 8, c = e & 255;
    float4 v = *(const float4*)(x + (grow0 + r) * 256 + c);
    unsigned short h0, l0, h1, l1, h2, l2, h3, l3;
    split1(v.x, h0, l0); split1(v.y, h1, l1);
    split1(v.z, h2, l2); split1(v.w, h3, l3);
    int idx = r * 256 + (((c >> 3) ^ (r & 31)) * 8) + (c & 7);
    ushort4 hv; hv.x = h0; hv.y = h1; hv.z = h2; hv.w = h3;
    ushort4 lv; lv.x = l0; lv.y = l1; lv.z = l2; lv.w = l3;
    *(ushort4*)&zh[idx] = hv;
    *(ushort4*)&zl[idx] = lv;
  }
  __syncthreads();

  const float* bnv[4] = {b1, b2, b3, b4};
  f32x4 acc[4][4];

  for (int layer = 0; layer < 5; ++layer) {
    const unsigned* pkl = pk + layer * 65536;
#pragma unroll
    for (int mt = 0; mt < 4; ++mt)
#pragma unroll
      for (int nt = 0; nt < 4; ++nt) acc[mt][nt] = (f32x4){0.f, 0.f, 0.f, 0.f};

#pragma unroll 2
    for (int kc = 0; kc < 8; ++kc) {
      short8 bh[4], bl[4], ah[4], al[4];
      const unsigned* pb = pkl + kc * 8192 + (wv * 4) * 512 + ln * 4;
#pragma unroll
      for (int nt = 0; nt < 4; ++nt) {
        bh[nt] = *(const short8*)(pb + nt * 512);
        bl[nt] = *(const short8*)(pb + nt * 512 + 256);
      }
#pragma unroll
      for (int mt = 0; mt < 4; ++mt) {
        int m = mt * 16 + n16;
        int idx = m * 256 + (((kc * 4 + quad) ^ (m & 31)) * 8);
        ah[mt] = *(const short8*)&zh[idx];
        al[mt] = *(const short8*)&zl[idx];
      }
#pragma unroll
      for (int mt = 0; mt < 4; ++mt)
#pragma unroll
        for (int nt = 0; nt < 4; ++nt) {
          acc[mt][nt] = __builtin_amdgcn_mfma_f32_16x16x32_bf16(ah[mt], bh[nt], acc[mt][nt], 0, 0, 0);
          acc[mt][nt] = __builtin_amdgcn_mfma_f32_16x16x32_bf16(al[mt], bh[nt], acc[mt][nt], 0, 0, 0);
          acc[mt][nt] = __builtin_amdgcn_mfma_f32_16x16x32_bf16(ah[mt], bl[nt], acc[mt][nt], 0, 0, 0);
        }
    }
    __syncthreads();  // all A-frag reads of this layer done

    // epilogue: bias / nonlinearity in registers, write next layer's planes
#pragma unroll
    for (int nt = 0; nt < 4; ++nt) {
      int col = wv * 64 + nt * 16 + n16;
      float badd = (layer == 0) ? b_in[col] : 0.0f;
      float bn = (layer < 4) ? bnv[layer][col] : 0.0f;
#pragma unroll
      for (int mt = 0; mt < 4; ++mt)
#pragma unroll
        for (int reg = 0; reg < 4; ++reg) {
          float v = acc[mt][nt][reg] + badd;
          float cv = (layer < 4) ? (v + tanhf_fast(v) + bn) : v;
          unsigned short hh, llo;
          split1(cv, hh, llo);
          int m = mt * 16 + quad * 4 + reg;
          int idx = m * 256 + (((col >> 3) ^ (m & 31)) * 8) + (col & 7);
          zh[idx] = hh;
          zl[idx] = llo;
        }
    }
    __syncthreads();
  }

  // ---- logits via MFMA: wave w reduces k-slice [w*64, w*64+64) ----
  f32x4 lacc[4];
#pragma unroll
  for (int mt = 0; mt < 4; ++mt) lacc[mt] = (f32x4){0.f, 0.f, 0.f, 0.f};
  const unsigned* pw = pk + 5 * 65536;
#pragma unroll
  for (int kk = 0; kk < 2; ++kk) {
    int kc = wv * 2 + kk;
    short8 bh = *(const short8*)(pw + kc * 512 + ln * 4);
    short8 bl = *(const short8*)(pw + kc * 512 + 256 + ln * 4);
#pragma unroll
    for (int mt = 0; mt < 4; ++mt) {
      int m = mt * 16 + n16;
      int idx = m * 256 + (((kc * 4 + quad) ^ (m & 31)) * 8);
      short8 ah = *(const short8*)&zh[idx];
      short8 al = *(const short8*)&zl[idx];
      lacc[mt] = __builtin_amdgcn_mfma_f32_16x16x32_bf16(ah, bh, lacc[mt], 0, 0, 0);
      lacc[mt] = __builtin_amdgcn_mfma_f32_16x16x32_bf16(al, bh, lacc[mt], 0, 0, 0);
      lacc[mt] = __builtin_amdgcn_mfma_f32_16x16x32_bf16(ah, bl, lacc[mt], 0, 0, 0);
    }
  }
  __syncthreads();  // done reading z planes; reuse LDS for partials
  float* pbuf = (float*)zh;  // 4 waves * 64 rows * 16 cols = 16 KB
#pragma unroll
  for (int mt = 0; mt < 4; ++mt)
#pragma unroll
    for (int reg = 0; reg < 4; ++reg)
      pbuf[wv * 1024 + (mt * 16 + quad * 4 + reg) * 16 + n16] = lacc[mt][reg];
  __syncthreads();
  if (t < 64) {
    int r = t;
    float lg[10];
    float mx = -1e30f;
#pragma unroll
    for (int j = 0; j < 10; ++j) {
      float s = b_out[j];
#pragma unroll
      for (int w2 = 0; w2 < 4; ++w2) s += pbuf[w2 * 1024 + r * 16 + j];
      lg[j] = s;
      mx = fmaxf(mx, s);
    }
    float sum = 0.f;
#pragma unroll
    for (int j = 0; j < 10; ++j) {
      lg[j] = __expf(lg[j] - mx);
      sum += lg[j];
    }
    float inv = 1.0f / sum;
    float* op = out + (grow0 + r) * 10;
#pragma unroll
    for (int j = 0; j < 10; ++j) op[j] = lg[j] * inv;
  }
}

extern "C" void kernel_launch(void* const* d_in, const int* in_sizes, int n_in,
                              void* d_out, int out_size, void* d_ws, size_t ws_size,
                              hipStream_t stream) {
  const float* x     = (const float*)d_in[0];
  const float* w_in  = (const float*)d_in[1];
  const float* b_in  = (const float*)d_in[2];
  const float* w_out = (const float*)d_in[3];
  const float* b_out = (const float*)d_in[4];
  const float* w1 = (const float*)d_in[5];
  const float* b1 = (const float*)d_in[6];
  const float* w2 = (const float*)d_in[7];
  const float* b2 = (const float*)d_in[8];
  const float* w3 = (const float*)d_in[9];
  const float* b3 = (const float*)d_in[10];
  const float* w4 = (const float*)d_in[11];
  const float* b4 = (const float*)d_in[12];
  float* out = (float*)d_out;

  // ws layout (3 MB): T @0 (1MB), X1 @1MB, X2 @2MB. pk (1.27MB) overlays T/X1
  // after they are dead (pack only reads X2).
  float* T  = (float*)d_ws;
  float* X1 = T + 4 * 65536;
  float* X2 = X1 + 4 * 65536;
  unsigned* pk = (unsigned*)d_ws;

  dim3 g(8, 8, 4), blk(256);
  // X0 = 2I - W;  T1 = W@X0;  X1 = X0@(2I-T1);  T2 = W@X1;  X2 = X1@(2I-T2)
  ns_gemm_k<<<g, blk, 0, stream>>>(w1, w2, w3, w4, w1, w2, w3, w4, T, 0, 1);
  ns_gemm_k<<<g, blk, 0, stream>>>(w1, w2, w3, w4, T, T + 65536, T + 131072, T + 196608, X1, 1, 1);
  ns_gemm_k<<<g, blk, 0, stream>>>(w1, w2, w3, w4, X1, X1 + 65536, X1 + 131072, X1 + 196608, T, 0, 0);
  ns_gemm_k<<<g, blk, 0, stream>>>(X1, X1 + 65536, X1 + 131072, X1 + 196608,
                                   T, T + 65536, T + 131072, T + 196608, X2, 0, 1);
  pack_k<<<1296, 256, 0, stream>>>(w_in, X2, w_out, pk);
  fused_k<<<1024, 256, 0, stream>>>(x, pk, b_in, b1, b2, b3, b4, b_out, out);
}

// Round 3
// 270.242 us; speedup vs baseline: 2.9457x; 1.1440x over previous
//
#include <hip/hip_runtime.h>
#include <math.h>

// B=65536 rows, DIM=256, OUT=10.
// z = x@w_in + b_in; 4x { z = (z + tanh(z) + b_i) @ inv(W_i) }; out = softmax(z@w_out + b_out).
// Newton on a linear system converges in one step => z = c @ W^{-1}.
// Round 3: swapped-operand MFMA (A=weights, B=z) so each lane's acc regs are 4
// consecutive cols of one z-row -> vectorized b64 epilogue writes; truncation
// split; branch-free tanh; cubic Newton-Schulz (3 GEMMs) with fused packing.

typedef __attribute__((ext_vector_type(8))) short short8;
typedef __attribute__((ext_vector_type(4))) float f32x4;

// ---- helpers ----
__device__ __forceinline__ float tanh_fast(float x) {
  // 1 - 2/(e^{2x}+1); large +x: e=inf -> 1; large -x: e=0 -> -1. No branches.
  float e = __expf(2.0f * x);
  return 1.0f - 2.0f * __builtin_amdgcn_rcpf(e + 1.0f);
}
__device__ __forceinline__ void split_tr(float c, unsigned short& h, unsigned short& l) {
  // truncation split: c = hi + lo + O(2^-16 |c|)
  unsigned u = __float_as_uint(c);
  h = (unsigned short)(u >> 16);
  float r = c - __uint_as_float(u & 0xffff0000u);
  l = (unsigned short)(__float_as_uint(r) >> 16);
}
__device__ __forceinline__ unsigned packw(float v0, float v1, int plane) {
  unsigned short h0, l0, h1, l1;
  split_tr(v0, h0, l0);
  split_tr(v1, h1, l1);
  unsigned a = plane ? (unsigned)l0 : (unsigned)h0;
  unsigned b = plane ? (unsigned)l1 : (unsigned)h1;
  return (b << 16) | a;
}

// ---------------- Phase 1: cubic Newton-Schulz, X1 = X0(3I-3Y+Y^2), Y=WX0 ----------------
// Generic batched 256x256x256 GEMM: D = A @ f(B), f(B) = bDiag*I - B (or B if bDiag==0);
// epilogue eMode: D = 3I - acc.
__global__ __launch_bounds__(256) void ns_gemm_k(
    const float* __restrict__ a0, const float* __restrict__ a1,
    const float* __restrict__ a2, const float* __restrict__ a3,
    const float* __restrict__ b0, const float* __restrict__ b1,
    const float* __restrict__ b2, const float* __restrict__ b3,
    float* __restrict__ D, float bDiag, int eMode) {
  __shared__ float As[32][17];
  __shared__ float Bs[16][33];
  int m = blockIdx.z;
  const float* A = (m == 0) ? a0 : (m == 1) ? a1 : (m == 2) ? a2 : a3;
  const float* B = (m == 0) ? b0 : (m == 1) ? b1 : (m == 2) ? b2 : b3;
  float* Dm = D + m * 65536;
  int t = threadIdx.x;
  int tx = t & 15, ty = t >> 4;
  int row0 = blockIdx.y * 32, col0 = blockIdx.x * 32;
  float acc00 = 0.f, acc01 = 0.f, acc10 = 0.f, acc11 = 0.f;
  for (int k0 = 0; k0 < 256; k0 += 16) {
#pragma unroll
    for (int half = 0; half < 2; ++half) {
      int e = t + half * 256;
      int r = e >> 4, kk = e & 15;
      As[r][kk] = A[(row0 + r) * 256 + k0 + kk];
      int k2 = e >> 5, c = e & 31;
      float w = B[(k0 + k2) * 256 + col0 + c];
      if (bDiag != 0.0f) w = (((k0 + k2) == (col0 + c)) ? bDiag : 0.0f) - w;
      Bs[k2][c] = w;
    }
    __syncthreads();
#pragma unroll
    for (int kk = 0; kk < 16; ++kk) {
      float av0 = As[ty][kk], av1 = As[ty + 16][kk];
      float bv0 = Bs[kk][tx], bv1 = Bs[kk][tx + 16];
      acc00 = fmaf(av0, bv0, acc00);
      acc01 = fmaf(av0, bv1, acc01);
      acc10 = fmaf(av1, bv0, acc10);
      acc11 = fmaf(av1, bv1, acc11);
    }
    __syncthreads();
  }
  if (eMode) {  // D = 3I - acc
    acc00 = (((row0 + ty) == (col0 + tx)) ? 3.f : 0.f) - acc00;
    acc01 = (((row0 + ty) == (col0 + tx + 16)) ? 3.f : 0.f) - acc01;
    acc10 = (((row0 + ty + 16) == (col0 + tx)) ? 3.f : 0.f) - acc10;
    acc11 = (((row0 + ty + 16) == (col0 + tx + 16)) ? 3.f : 0.f) - acc11;
  }
  Dm[(row0 + ty) * 256 + col0 + tx] = acc00;
  Dm[(row0 + ty) * 256 + col0 + tx + 16] = acc01;
  Dm[(row0 + ty + 16) * 256 + col0 + tx] = acc10;
  Dm[(row0 + ty + 16) * 256 + col0 + tx + 16] = acc11;
}

// X1 = (2I - W) @ V, packed directly into MFMA fragment order (layers 1..4).
// pk layout (dwords): layer*65536 + kc*8192 + nt*512 + plane*256 + lane*4 + d
// lane (quad=lane>>4, n=lane&15) dword d holds W[kc*32+quad*8+2d][nt*16+n] (lo16)
// and W[..+2d+1][..] (hi16); plane0=hi split half, plane1=lo split half.
__global__ __launch_bounds__(256) void ns_pack_k(
    const float* __restrict__ w1a, const float* __restrict__ w2a,
    const float* __restrict__ w3a, const float* __restrict__ w4a,
    const float* __restrict__ V, unsigned* __restrict__ pk) {
  __shared__ float As[32][17];
  __shared__ float Bs[16][33];
  __shared__ float Dt[32][33];
  int m = blockIdx.z;
  const float* A = (m == 0) ? w1a : (m == 1) ? w2a : (m == 2) ? w3a : w4a;
  const float* B = V + m * 65536;
  int t = threadIdx.x;
  int tx = t & 15, ty = t >> 4;
  int row0 = blockIdx.y * 32, col0 = blockIdx.x * 32;
  float acc00 = 0.f, acc01 = 0.f, acc10 = 0.f, acc11 = 0.f;
  for (int k0 = 0; k0 < 256; k0 += 16) {
#pragma unroll
    for (int half = 0; half < 2; ++half) {
      int e = t + half * 256;
      int r = e >> 4, kk = e & 15;
      float v = A[(row0 + r) * 256 + k0 + kk];
      v = (((row0 + r) == (k0 + kk)) ? 2.0f : 0.0f) - v;  // 2I - W
      As[r][kk] = v;
      int k2 = e >> 5, c = e & 31;
      Bs[k2][c] = B[(k0 + k2) * 256 + col0 + c];
    }
    __syncthreads();
#pragma unroll
    for (int kk = 0; kk < 16; ++kk) {
      float av0 = As[ty][kk], av1 = As[ty + 16][kk];
      float bv0 = Bs[kk][tx], bv1 = Bs[kk][tx + 16];
      acc00 = fmaf(av0, bv0, acc00);
      acc01 = fmaf(av0, bv1, acc01);
      acc10 = fmaf(av1, bv0, acc10);
      acc11 = fmaf(av1, bv1, acc11);
    }
    __syncthreads();
  }
  Dt[ty][tx] = acc00;
  Dt[ty][tx + 16] = acc01;
  Dt[ty + 16][tx] = acc10;
  Dt[ty + 16][tx + 16] = acc11;
  __syncthreads();
  int kc = row0 >> 5;
#pragma unroll
  for (int i = 0; i < 4; ++i) {
    int q = i * 256 + t;               // 0..1023
    int nt2 = q >> 9;                  // 0..1
    int plane = (q >> 8) & 1;
    int lane = (q >> 2) & 63;
    int d = q & 3;
    int lr = (lane >> 4) * 8 + d * 2;  // local row (even)
    int lc = nt2 * 16 + (lane & 15);   // local col
    unsigned word = packw(Dt[lr][lc], Dt[lr + 1][lc], plane);
    pk[(m + 1) * 65536 + kc * 8192 + ((col0 >> 4) + nt2) * 512 + plane * 256 + lane * 4 + d] = word;
  }
}

// Pack w_in (layer 0) and w_out (at 5*65536, cols>=10 zero).
__global__ void pack_io_k(const float* __restrict__ w_in, const float* __restrict__ w_out,
                          unsigned* __restrict__ pk) {
  int idx = blockIdx.x * 256 + threadIdx.x;  // 0..69631
  if (idx < 65536) {
    int kc = idx >> 13;
    int nt = (idx >> 9) & 15;
    int plane = (idx >> 8) & 1;
    int lane = (idx >> 2) & 63;
    int d = idx & 3;
    int n = nt * 16 + (lane & 15);
    int kb = kc * 32 + (lane >> 4) * 8 + d * 2;
    pk[idx] = packw(w_in[kb * 256 + n], w_in[(kb + 1) * 256 + n], plane);
  } else {
    int r2 = idx - 65536;  // 0..4095
    int kc = r2 >> 9;
    int plane = (r2 >> 8) & 1;
    int lane = (r2 >> 2) & 63;
    int d = r2 & 3;
    int n = lane & 15;
    int kb = kc * 32 + (lane >> 4) * 8 + d * 2;
    float v0 = (n < 10) ? w_out[kb * 10 + n] : 0.0f;
    float v1 = (n < 10) ? w_out[(kb + 1) * 10 + n] : 0.0f;
    pk[5 * 65536 + r2] = packw(v0, v1, plane);
  }
}

// ---------------- Phase 2: fused pipeline (MFMA, A=weights, B=z) ----------------
// 64 rows/block, 4 waves; wave w owns cols [w*64, w*64+64).
// z in LDS as two bf16 planes, 16B-chunk XOR swizzle:
//   idx16(r,k) = r*256 + ((k>>3) ^ (r&31))*8 + (k&7)
// With A=weights, B=z: D[row=quad*4+reg][col=lane&15] = (z@W)[zrow=n16][wcol=quad*4+reg]
// -> each lane's 4 acc regs are 4 consecutive output cols of one z-row.
__global__ __launch_bounds__(256, 2) void fused_k(
    const float* __restrict__ x, const unsigned* __restrict__ pk,
    const float* __restrict__ b_in,
    const float* __restrict__ b1, const float* __restrict__ b2,
    const float* __restrict__ b3, const float* __restrict__ b4,
    const float* __restrict__ b_out, float* __restrict__ out) {
  __shared__ unsigned short zh[64 * 256];
  __shared__ unsigned short zl[64 * 256];
  const int t = threadIdx.x;
  const int ln = t & 63;
  const int wv = t >> 6;
  const int quad = ln >> 4;
  const int n16 = ln & 15;
  const int grow0 = blockIdx.x * 64;

  // ---- stage x as split bf16 planes ----
#pragma unroll
  for (int i = 0; i < 16; ++i) {
    int e = i * 1024 + t * 4;
    int r = e >> 8, c = e & 255;
    float4 v = *(const float4*)(x + (grow0 + r) * 256 + c);
    unsigned short h0, l0, h1, l1, h2, l2, h3, l3;
    split_tr(v.x, h0, l0); split_tr(v.y, h1, l1);
    split_tr(v.z, h2, l2); split_tr(v.w, h3, l3);
    int idx = r * 256 + (((c >> 3) ^ (r & 31)) * 8) + (c & 7);
    *(ushort4*)&zh[idx] = make_ushort4(h0, h1, h2, h3);
    *(ushort4*)&zl[idx] = make_ushort4(l0, l1, l2, l3);
  }
  __syncthreads();

  const float* bnv[4] = {b1, b2, b3, b4};
  f32x4 acc[4][4];

  for (int layer = 0; layer < 5; ++layer) {
    const unsigned* pkl = pk + layer * 65536 + wv * 2048 + ln * 4;
#pragma unroll
    for (int mt = 0; mt < 4; ++mt)
#pragma unroll
      for (int nt = 0; nt < 4; ++nt) acc[mt][nt] = (f32x4){0.f, 0.f, 0.f, 0.f};

#pragma unroll 2
    for (int kc = 0; kc < 8; ++kc) {
      short8 wh[4], wl[4], zfh[4], zfl[4];
      const unsigned* pb = pkl + kc * 8192;
#pragma unroll
      for (int nt = 0; nt < 4; ++nt) {
        wh[nt] = *(const short8*)(pb + nt * 512);
        wl[nt] = *(const short8*)(pb + nt * 512 + 256);
      }
#pragma unroll
      for (int mt = 0; mt < 4; ++mt) {
        int m = mt * 16 + n16;
        int idx = m * 256 + (((kc * 4 + quad) ^ (m & 31)) * 8);
        zfh[mt] = *(const short8*)&zh[idx];
        zfl[mt] = *(const short8*)&zl[idx];
      }
#pragma unroll
      for (int mt = 0; mt < 4; ++mt)
#pragma unroll
        for (int nt = 0; nt < 4; ++nt) {
          acc[mt][nt] = __builtin_amdgcn_mfma_f32_16x16x32_bf16(wh[nt], zfh[mt], acc[mt][nt], 0, 0, 0);
          acc[mt][nt] = __builtin_amdgcn_mfma_f32_16x16x32_bf16(wh[nt], zfl[mt], acc[mt][nt], 0, 0, 0);
          acc[mt][nt] = __builtin_amdgcn_mfma_f32_16x16x32_bf16(wl[nt], zfh[mt], acc[mt][nt], 0, 0, 0);
        }
    }
    __syncthreads();  // all z reads of this layer done

    // epilogue: lane owns rows mt*16+n16, cols colb..colb+3 (vectorized b64 writes)
#pragma unroll
    for (int nt = 0; nt < 4; ++nt) {
      int colb = wv * 64 + nt * 16 + quad * 4;
      float4 bi = make_float4(0.f, 0.f, 0.f, 0.f);
      float4 bn4 = bi;
      if (layer == 0) bi = *(const float4*)(b_in + colb);
      if (layer < 4) bn4 = *(const float4*)(bnv[layer] + colb);
#pragma unroll
      for (int mt = 0; mt < 4; ++mt) {
        int row = mt * 16 + n16;
        float v0 = acc[mt][nt][0] + bi.x;
        float v1 = acc[mt][nt][1] + bi.y;
        float v2 = acc[mt][nt][2] + bi.z;
        float v3 = acc[mt][nt][3] + bi.w;
        if (layer < 4) {
          v0 = v0 + tanh_fast(v0) + bn4.x;
          v1 = v1 + tanh_fast(v1) + bn4.y;
          v2 = v2 + tanh_fast(v2) + bn4.z;
          v3 = v3 + tanh_fast(v3) + bn4.w;
        }
        unsigned short h0, l0, h1, l1, h2, l2, h3, l3;
        split_tr(v0, h0, l0); split_tr(v1, h1, l1);
        split_tr(v2, h2, l2); split_tr(v3, h3, l3);
        int idx = row * 256 + (((colb >> 3) ^ (row & 31)) * 8) + (colb & 7);
        *(ushort4*)&zh[idx] = make_ushort4(h0, h1, h2, h3);
        *(ushort4*)&zl[idx] = make_ushort4(l0, l1, l2, l3);
      }
    }
    __syncthreads();
  }

  // ---- logits: wave w reduces k-slice [w*64, w*64+64) ----
  f32x4 lacc[4];
#pragma unroll
  for (int mt = 0; mt < 4; ++mt) lacc[mt] = (f32x4){0.f, 0.f, 0.f, 0.f};
  const unsigned* pw = pk + 5 * 65536 + ln * 4;
#pragma unroll
  for (int kk = 0; kk < 2; ++kk) {
    int kc = wv * 2 + kk;
    short8 wh = *(const short8*)(pw + kc * 512);
    short8 wl = *(const short8*)(pw + kc * 512 + 256);
#pragma unroll
    for (int mt = 0; mt < 4; ++mt) {
      int m = mt * 16 + n16;
      int idx = m * 256 + (((kc * 4 + quad) ^ (m & 31)) * 8);
      short8 zfh = *(const short8*)&zh[idx];
      short8 zfl = *(const short8*)&zl[idx];
      lacc[mt] = __builtin_amdgcn_mfma_f32_16x16x32_bf16(wh, zfh, lacc[mt], 0, 0, 0);
      lacc[mt] = __builtin_amdgcn_mfma_f32_16x16x32_bf16(wh, zfl, lacc[mt], 0, 0, 0);
      lacc[mt] = __builtin_amdgcn_mfma_f32_16x16x32_bf16(wl, zfh, lacc[mt], 0, 0, 0);
    }
  }
  __syncthreads();  // done reading z planes
  float* pbuf = (float*)zh;  // [wave][row][16] = 16 KB
#pragma unroll
  for (int mt = 0; mt < 4; ++mt) {
    int addr = wv * 1024 + (mt * 16 + n16) * 16 + quad * 4;
    *(f32x4*)&pbuf[addr] = lacc[mt];  // lane's regs = 4 consecutive logit cols
  }
  __syncthreads();
  if (t < 64) {
    int r = t;
    float lg[10];
    float mx = -1e30f;
#pragma unroll
    for (int j = 0; j < 10; ++j) {
      float s = b_out[j];
#pragma unroll
      for (int w2 = 0; w2 < 4; ++w2) s += pbuf[w2 * 1024 + r * 16 + j];
      lg[j] = s;
      mx = fmaxf(mx, s);
    }
    float sum = 0.f;
#pragma unroll
    for (int j = 0; j < 10; ++j) {
      lg[j] = __expf(lg[j] - mx);
      sum += lg[j];
    }
    float inv = 1.0f / sum;
    float* op = out + (grow0 + r) * 10;
#pragma unroll
    for (int j = 0; j < 10; ++j) op[j] = lg[j] * inv;
  }
}

extern "C" void kernel_launch(void* const* d_in, const int* in_sizes, int n_in,
                              void* d_out, int out_size, void* d_ws, size_t ws_size,
                              hipStream_t stream) {
  const float* x     = (const float*)d_in[0];
  const float* w_in  = (const float*)d_in[1];
  const float* b_in  = (const float*)d_in[2];
  const float* w_out = (const float*)d_in[3];
  const float* b_out = (const float*)d_in[4];
  const float* w1 = (const float*)d_in[5];
  const float* b1 = (const float*)d_in[6];
  const float* w2 = (const float*)d_in[7];
  const float* b2 = (const float*)d_in[8];
  const float* w3 = (const float*)d_in[9];
  const float* b3 = (const float*)d_in[10];
  const float* w4 = (const float*)d_in[11];
  const float* b4 = (const float*)d_in[12];
  float* out = (float*)d_out;

  // ws layout (dwords): pk [0, 331776) ; T [331776, +262144) ; U [593920, +262144)
  unsigned* pk = (unsigned*)d_ws;
  float* T = (float*)d_ws + 331776;
  float* U = T + 262144;

  dim3 g(8, 8, 4), blk(256);
  pack_io_k<<<272, 256, 0, stream>>>(w_in, w_out, pk);
  // Y = W @ (2I - W)
  ns_gemm_k<<<g, blk, 0, stream>>>(w1, w2, w3, w4, w1, w2, w3, w4, T, 2.0f, 0);
  // V = 3I - Y @ (3I - Y)  ( = 3I - 3Y + Y^2 )
  ns_gemm_k<<<g, blk, 0, stream>>>(T, T + 65536, T + 131072, T + 196608,
                                   T, T + 65536, T + 131072, T + 196608, U, 3.0f, 1);
  // X1 = (2I - W) @ V, packed into pk layers 1..4
  ns_pack_k<<<g, blk, 0, stream>>>(w1, w2, w3, w4, U, pk);
  fused_k<<<1024, 256, 0, stream>>>(x, pk, b_in, b1, b2, b3, b4, b_out, out);
}